// Round 11
// baseline (263.457 us; speedup 1.0000x reference)
//
#include <hip/hip_runtime.h>
#include <math.h>

#define D_IN 5
#define H 64
#define GSH 8        // 256-node groups for CSR build
#define MAXG 512     // max groups per side
#define CHUNK 4096   // edges per block in count/scatter

using f32x4 = __attribute__((ext_vector_type(4))) float;
using short8 = __attribute__((ext_vector_type(8))) short;

__device__ inline short f2bf(float f) {
  unsigned u = __builtin_bit_cast(unsigned, f);
  u += 0x7fffu + ((u >> 16) & 1u);  // round-to-nearest-even
  return (short)(u >> 16);
}
__device__ inline float bf2f(short s) {
  return __builtin_bit_cast(float, ((unsigned)(unsigned short)s) << 16);
}
__device__ inline short8 cvt8(f32x4 a, f32x4 b) {
  short8 r;
  r[0] = f2bf(a[0]); r[1] = f2bf(a[1]); r[2] = f2bf(a[2]); r[3] = f2bf(a[3]);
  r[4] = f2bf(b[0]); r[5] = f2bf(b[1]); r[6] = f2bf(b[2]); r[7] = f2bf(b[3]);
  return r;
}
__device__ inline void acc16(float* m, const short8& a, const short8& b) {
#pragma unroll
  for (int i = 0; i < 8; ++i) {
    m[i] += bf2f(a[i]);
    m[8 + i] += bf2f(b[i]);
  }
}

// ---------------- input projection ----------------
__global__ __launch_bounds__(256) void proj_kernel(
    const float* __restrict__ x, const float* __restrict__ W,
    const float* __restrict__ b, short* __restrict__ out, int n) {
  __shared__ float Ws[D_IN * H];
  __shared__ float bs[H];
  int t = threadIdx.x;
  for (int i = t; i < D_IN * H; i += 256) Ws[i] = W[i];
  if (t < H) bs[t] = b[t];
  __syncthreads();
  int idx = blockIdx.x * 256 + t;
  int node = idx >> 6;
  int h = idx & 63;
  if (node >= n) return;
  const float* xr = x + (size_t)node * D_IN;
  float acc = bs[h];
#pragma unroll
  for (int d = 0; d < D_IN; ++d) acc = fmaf(xr[d], Ws[d * H + h], acc);
  out[(size_t)node * H + h] = f2bf(acc);
}

// ---------------- CSR build v4: block-aggregated two-level counting sort ----------------
__global__ __launch_bounds__(256) void group_count_kernel(
    const int* __restrict__ src, const int* __restrict__ dst,
    int* __restrict__ gcntS, int* __restrict__ gcntD,
    int* __restrict__ baseS, int* __restrict__ baseD,
    int nGS, int nGD, int E) {
  __shared__ int hS[MAXG], hD[MAXG];
  int t = threadIdx.x;
  int b = blockIdx.x;
  for (int i = t; i < MAXG; i += 256) { hS[i] = 0; hD[i] = 0; }
  __syncthreads();
  int e0 = b * CHUNK;
#pragma unroll
  for (int it = 0; it < CHUNK / 1024; ++it) {
    int e = e0 + (it * 256 + t) * 4;
    if (e + 4 <= E) {
      int4 s4 = *(const int4*)(src + e);
      int4 d4 = *(const int4*)(dst + e);
      atomicAdd(&hS[s4.x >> GSH], 1);
      atomicAdd(&hS[s4.y >> GSH], 1);
      atomicAdd(&hS[s4.z >> GSH], 1);
      atomicAdd(&hS[s4.w >> GSH], 1);
      atomicAdd(&hD[d4.x >> GSH], 1);
      atomicAdd(&hD[d4.y >> GSH], 1);
      atomicAdd(&hD[d4.z >> GSH], 1);
      atomicAdd(&hD[d4.w >> GSH], 1);
    } else {
      for (int i = 0; i < 4; ++i) {
        int ee = e + i;
        if (ee < E) {
          atomicAdd(&hS[src[ee] >> GSH], 1);
          atomicAdd(&hD[dst[ee] >> GSH], 1);
        }
      }
    }
  }
  __syncthreads();
  for (int g = t; g < nGS; g += 256) {
    int h = hS[g];
    baseS[(size_t)b * nGS + g] = h ? atomicAdd(&gcntS[g], h) : 0;
  }
  for (int g = t; g < nGD; g += 256) {
    int h = hD[g];
    baseD[(size_t)b * nGD + g] = h ? atomicAdd(&gcntD[g], h) : 0;
  }
}

__global__ __launch_bounds__(512) void goff_scan_kernel(
    const int* __restrict__ gcntS, int* __restrict__ GoffS, int nGS,
    const int* __restrict__ gcntD, int* __restrict__ GoffD, int nGD) {
  const int* c = blockIdx.x ? gcntD : gcntS;
  int* G = blockIdx.x ? GoffD : GoffS;
  int n = blockIdx.x ? nGD : nGS;
  __shared__ int tmp[512];
  int t = threadIdx.x;
  int v = (t < n) ? c[t] : 0;
  tmp[t] = v;
  __syncthreads();
  for (int s = 1; s < 512; s <<= 1) {
    int add = (t >= s) ? tmp[t - s] : 0;
    __syncthreads();
    tmp[t] += add;
    __syncthreads();
  }
  if (t < n) G[t] = tmp[t] - v;
  if (t == n - 1) G[n] = tmp[t];
}

__global__ __launch_bounds__(256) void stage_scatter_kernel(
    const int* __restrict__ src, const int* __restrict__ dst,
    const int* __restrict__ GoffS, const int* __restrict__ GoffD,
    const int* __restrict__ baseS, const int* __restrict__ baseD,
    uint2* __restrict__ stageS, uint2* __restrict__ stageD,
    int nGS, int nGD, int E) {
  __shared__ int cS[MAXG], cD[MAXG];
  int t = threadIdx.x;
  int b = blockIdx.x;
  for (int g = t; g < nGS; g += 256) cS[g] = GoffS[g] + baseS[(size_t)b * nGS + g];
  for (int g = t; g < nGD; g += 256) cD[g] = GoffD[g] + baseD[(size_t)b * nGD + g];
  __syncthreads();
  int e0 = b * CHUNK;
#pragma unroll
  for (int it = 0; it < CHUNK / 1024; ++it) {
    int e = e0 + (it * 256 + t) * 4;
    if (e + 4 <= E) {
      int4 s4 = *(const int4*)(src + e);
      int4 d4 = *(const int4*)(dst + e);
      int pS0 = atomicAdd(&cS[s4.x >> GSH], 1);
      int pS1 = atomicAdd(&cS[s4.y >> GSH], 1);
      int pS2 = atomicAdd(&cS[s4.z >> GSH], 1);
      int pS3 = atomicAdd(&cS[s4.w >> GSH], 1);
      int pD0 = atomicAdd(&cD[d4.x >> GSH], 1);
      int pD1 = atomicAdd(&cD[d4.y >> GSH], 1);
      int pD2 = atomicAdd(&cD[d4.z >> GSH], 1);
      int pD3 = atomicAdd(&cD[d4.w >> GSH], 1);
      stageS[pS0] = make_uint2(d4.x, s4.x);
      stageS[pS1] = make_uint2(d4.y, s4.y);
      stageS[pS2] = make_uint2(d4.z, s4.z);
      stageS[pS3] = make_uint2(d4.w, s4.w);
      stageD[pD0] = make_uint2(s4.x, d4.x);
      stageD[pD1] = make_uint2(s4.y, d4.y);
      stageD[pD2] = make_uint2(s4.z, d4.z);
      stageD[pD3] = make_uint2(s4.w, d4.w);
    } else {
      for (int i = 0; i < 4; ++i) {
        int ee = e + i;
        if (ee < E) {
          int s = src[ee], d = dst[ee];
          int pS = atomicAdd(&cS[s >> GSH], 1);
          int pD = atomicAdd(&cD[d >> GSH], 1);
          stageS[pS] = make_uint2(d, s);
          stageD[pD] = make_uint2(s, d);
        }
      }
    }
  }
}

// pass D: one block per (side,group): node histogram + scan -> off[], then scatter col.
__global__ __launch_bounds__(256) void finalize_group_kernel(
    const uint2* __restrict__ stageS, const int* __restrict__ GoffS, int nGS, int n_mch,
    int* __restrict__ off_mch, int* __restrict__ col_mch,
    const uint2* __restrict__ stageD, const int* __restrict__ GoffD, int n_mft,
    int* __restrict__ off_mft, int* __restrict__ col_mft, int E) {
  int b = blockIdx.x;
  const uint2* stage;
  const int* Goff;
  int n, g;
  int* off;
  int* col;
  if (b >= nGS) {
    g = b - nGS;
    stage = stageD; Goff = GoffD; n = n_mft; off = off_mft; col = col_mft;
  } else {
    g = b;
    stage = stageS; Goff = GoffS; n = n_mch; off = off_mch; col = col_mch;
  }
  int base = Goff[g];
  int cnt = Goff[g + 1] - base;
  int t = threadIdx.x;

  __shared__ int tmp[256];
  __shared__ int curs[256];
  tmp[t] = 0;
  __syncthreads();
  for (int j = t; j < cnt; j += 256) {
    uint2 p = stage[base + j];
    atomicAdd(&tmp[p.y & 255], 1);
  }
  __syncthreads();
  int v = tmp[t];
  __syncthreads();
  tmp[t] = v;
  __syncthreads();
  for (int s = 1; s < 256; s <<= 1) {
    int add = (t >= s) ? tmp[t - s] : 0;
    __syncthreads();
    tmp[t] += add;
    __syncthreads();
  }
  int excl = tmp[t] - v;
  int gnode = (g << GSH) + t;
  if (gnode < n) {
    off[gnode] = base + excl;
    if (gnode == n - 1) off[n] = E;
  }
  curs[t] = base + excl;
  __syncthreads();
  for (int j = t; j < cnt; j += 256) {
    uint2 p = stage[base + j];
    int pos = atomicAdd(&curs[p.y & 255], 1);
    col[pos] = (int)p.x;
  }
}

// ---------------- fused SAGE via MFMA: per-node registers, LDS weights, 8-deep burst ----
template <bool RELU>
__global__ __launch_bounds__(256) void sage_dual_kernel(
    const short* __restrict__ xsrcA, const short* __restrict__ xdstA,
    const int* __restrict__ offA, const int* __restrict__ colA,
    const float* __restrict__ WlA, const float* __restrict__ blA,
    const float* __restrict__ WrA, short* __restrict__ outA, int nA, int blkA,
    const short* __restrict__ xsrcB, const short* __restrict__ xdstB,
    const int* __restrict__ offB, const int* __restrict__ colB,
    const float* __restrict__ WlB, const float* __restrict__ blB,
    const float* __restrict__ WrB, short* __restrict__ outB, int nB) {
  bool isB = ((int)blockIdx.x >= blkA);
  int bid = isB ? (int)blockIdx.x - blkA : (int)blockIdx.x;
  const short* xsrc = isB ? xsrcB : xsrcA;
  const short* xdst = isB ? xdstB : xdstA;
  const int* off = isB ? offB : offA;
  const int* col = isB ? colB : colA;
  const float* Wl = isB ? WlB : WlA;
  const float* bl = isB ? blB : blA;
  const float* Wr = isB ? WrB : WrA;
  short* out = isB ? outB : outA;
  int n_dst = isB ? nB : nA;

  int t = threadIdx.x;
  int wave = t >> 6, lane = t & 63;
  int g = lane >> 4, c = lane & 15;

  __shared__ short8 lds_bw[4][4][64];
  for (int i = t; i < 4 * 4 * 64; i += 256) {
    int kt = i >> 8;
    int nn = (i >> 6) & 3;
    int ln = i & 63;
    int gg = ln >> 4, cc = ln & 15;
    const float* Wsrc = (kt < 2) ? Wl : Wr;
    int kbase = (kt & 1) * 32 + 8 * gg;
    short8 w;
#pragma unroll
    for (int j = 0; j < 8; ++j)
      w[j] = f2bf(Wsrc[(kbase + j) * H + 16 * nn + cc]);
    lds_bw[kt][nn][ln] = w;
  }
  __syncthreads();

  int node0 = (bid * 4 + wave) * 16;
  if (node0 >= n_dst) return;

  int mynode = node0 + c;
  int nd = (mynode < n_dst) ? mynode : 0;

  float blv[4];
#pragma unroll
  for (int n = 0; n < 4; ++n) blv[n] = bl[16 * n + c];

  // hoist root-row loads
  const short8* pr = (const short8*)(xdst + (size_t)nd * H + 8 * g);
  short8 r0 = pr[0], r1 = pr[4];

  // mean-aggregate: 8-neighbor bursts (16 loads in flight) + col prefetch a burst ahead
  float m[16];
#pragma unroll
  for (int i = 0; i < 16; ++i) m[i] = 0.f;
  int beg = off[nd];
  int n_nb = off[nd + 1] - beg;
  if (n_nb > 0) {
    int last = n_nb - 1;
    int idx[8];
#pragma unroll
    for (int q = 0; q < 8; ++q) idx[q] = col[beg + (q < last ? q : last)];
    for (int jb = 0; jb < n_nb; jb += 8) {
      short8 a[8], bb[8];
      // issue all 16 row loads for this burst
#pragma unroll
      for (int q = 0; q < 8; ++q) {
        const short8* p = (const short8*)(xsrc + (size_t)idx[q] * H + 8 * g);
        a[q] = p[0];
        bb[q] = p[4];
      }
      // prefetch next burst's col indices (overlaps row loads)
      int jn = jb + 8;
      if (jn < n_nb) {
#pragma unroll
        for (int q = 0; q < 8; ++q) {
          int j = jn + q;
          idx[q] = col[beg + (j < last ? j : last)];
        }
      }
      int rem = n_nb - jb;
#pragma unroll
      for (int q = 0; q < 8; ++q)
        if (rem > q) acc16(m, a[q], bb[q]);
    }
  }
  float invd = (n_nb > 0) ? 1.f / (float)n_nb : 1.f;
  f32x4 m0, m1, m2, m3;
#pragma unroll
  for (int i = 0; i < 4; ++i) {
    m0[i] = m[i] * invd;
    m1[i] = m[4 + i] * invd;
    m2[i] = m[8 + i] * invd;
    m3[i] = m[12 + i] * invd;
  }

  short8 af[4];
  af[0] = cvt8(m0, m1);
  af[1] = cvt8(m2, m3);
  af[2] = r0;
  af[3] = r1;

  f32x4 zero4 = {0.f, 0.f, 0.f, 0.f};
  f32x4 acc[4];
#pragma unroll
  for (int n = 0; n < 4; ++n) acc[n] = zero4;
#pragma unroll
  for (int kt = 0; kt < 4; ++kt)
#pragma unroll
    for (int n = 0; n < 4; ++n)
      acc[n] = __builtin_amdgcn_mfma_f32_16x16x32_bf16(af[kt], lds_bw[kt][n][lane], acc[n], 0, 0, 0);

#pragma unroll
  for (int n = 0; n < 4; ++n)
#pragma unroll
    for (int r = 0; r < 4; ++r) {
      float o = acc[n][r] + blv[n];
      if (RELU) o = fmaxf(o, 0.f);
      int row = node0 + 4 * g + r;
      if (row < n_dst) out[(size_t)row * H + 16 * n + c] = f2bf(o);
    }
}

// ---------------- edge classifier via MFMA, LDS weights + 2-deep tile pipeline --------
__global__ __launch_bounds__(256) void edge_mlp_mfma_kernel(
    const short* __restrict__ mch2, const short* __restrict__ mft2,
    const int* __restrict__ src, const int* __restrict__ dst,
    const float* __restrict__ W1, const float* __restrict__ b1,
    const float* __restrict__ W2, const float* __restrict__ b2,
    float* __restrict__ out, int E) {
  int t = threadIdx.x;
  int wave = t >> 6, lane = t & 63;
  int g = lane >> 4, c = lane & 15;

  __shared__ short8 lds_bw[4][4][64];
  for (int i = t; i < 4 * 4 * 64; i += 256) {
    int kt = i >> 8;
    int nn = (i >> 6) & 3;
    int ln = i & 63;
    int gg = ln >> 4, cc = ln & 15;
    int kbase = 32 * kt + 8 * gg;
    short8 w;
#pragma unroll
    for (int j = 0; j < 8; ++j)
      w[j] = f2bf(W1[(kbase + j) * H + 16 * nn + cc]);
    lds_bw[kt][nn][ln] = w;
  }
  __syncthreads();

  float b1v[4], w2v[4];
#pragma unroll
  for (int n = 0; n < 4; ++n) { b1v[n] = b1[16 * n + c]; w2v[n] = W2[16 * n + c]; }
  float b2v = b2[0];
  f32x4 zero4 = {0.f, 0.f, 0.f, 0.f};

  int ntiles = (E + 15) >> 4;
  int stride = gridDim.x * 4;
  int t0 = blockIdx.x * 4 + wave;
  if (t0 >= ntiles) return;

  auto loadIdx = [&](int tile, int& s, int& d) {
    int e = tile * 16 + c;
    int ee = (e < E) ? e : E - 1;
    s = src[ee];
    d = dst[ee];
  };
  auto loadRows = [&](int s, int d, short8* af) {
    const short8* pa = (const short8*)(mch2 + (size_t)s * H + 8 * g);
    const short8* pb = (const short8*)(mft2 + (size_t)d * H + 8 * g);
    af[0] = pa[0];
    af[1] = pa[4];
    af[2] = pb[0];
    af[3] = pb[4];
  };

  int sA, dA, sB, dB;
  short8 afA[4];
  loadIdx(t0, sA, dA);
  loadRows(sA, dA, afA);
  {
    int tB = t0 + stride;
    loadIdx((tB < ntiles) ? tB : (ntiles - 1), sB, dB);
  }

  for (int tile = t0; tile < ntiles; tile += stride) {
    short8 afB[4];
    loadRows(sB, dB, afB);
    int sC, dC;
    {
      int tC = tile + 2 * stride;
      loadIdx((tC < ntiles) ? tC : (ntiles - 1), sC, dC);
    }

    f32x4 acc[4];
#pragma unroll
    for (int n = 0; n < 4; ++n) acc[n] = zero4;
#pragma unroll
    for (int kt = 0; kt < 4; ++kt)
#pragma unroll
      for (int n = 0; n < 4; ++n)
        acc[n] = __builtin_amdgcn_mfma_f32_16x16x32_bf16(afA[kt], lds_bw[kt][n][lane], acc[n], 0, 0, 0);

    float part[4];
#pragma unroll
    for (int r = 0; r < 4; ++r) {
      float sum = 0.f;
#pragma unroll
      for (int n = 0; n < 4; ++n) {
        float v = acc[n][r] + b1v[n];
        v = fmaxf(v, 0.f);
        sum = fmaf(v, w2v[n], sum);
      }
      part[r] = sum;
    }
#pragma unroll
    for (int r = 0; r < 4; ++r) {
      part[r] += __shfl_xor(part[r], 1);
      part[r] += __shfl_xor(part[r], 2);
      part[r] += __shfl_xor(part[r], 4);
      part[r] += __shfl_xor(part[r], 8);
    }
    if (c < 4) {
      int eo = tile * 16 + 4 * g + c;
      float v = (c == 0) ? part[0] : (c == 1) ? part[1] : (c == 2) ? part[2] : part[3];
      if (eo < E) out[eo] = 1.f / (1.f + expf(-(v + b2v)));
    }

#pragma unroll
    for (int i = 0; i < 4; ++i) afA[i] = afB[i];
    sB = sC;
    dB = dC;
  }
}

extern "C" void kernel_launch(void* const* d_in, const int* in_sizes, int n_in,
                              void* d_out, int out_size, void* d_ws, size_t ws_size,
                              hipStream_t stream) {
  const float* x_mch = (const float*)d_in[0];
  const float* x_mft = (const float*)d_in[1];
  const int* eidx = (const int*)d_in[2];
  const int E = in_sizes[2] / 2;
  const int* src = eidx;
  const int* dst = eidx + E;
  const float* W_mch = (const float*)d_in[3];
  const float* b_mch = (const float*)d_in[4];
  const float* W_mft = (const float*)d_in[5];
  const float* b_mft = (const float*)d_in[6];
  const float* c1m_Wl = (const float*)d_in[7];
  const float* c1m_bl = (const float*)d_in[8];
  const float* c1m_Wr = (const float*)d_in[9];
  const float* c1r_Wl = (const float*)d_in[10];
  const float* c1r_bl = (const float*)d_in[11];
  const float* c1r_Wr = (const float*)d_in[12];
  const float* c2m_Wl = (const float*)d_in[13];
  const float* c2m_bl = (const float*)d_in[14];
  const float* c2m_Wr = (const float*)d_in[15];
  const float* c2r_Wl = (const float*)d_in[16];
  const float* c2r_bl = (const float*)d_in[17];
  const float* c2r_Wr = (const float*)d_in[18];
  const float* ec_W1 = (const float*)d_in[19];
  const float* ec_b1 = (const float*)d_in[20];
  const float* ec_W2 = (const float*)d_in[21];
  const float* ec_b2 = (const float*)d_in[22];

  const int n_mch = in_sizes[0] / D_IN;
  const int n_mft = in_sizes[1] / D_IN;
  const int nGS = (n_mch + 255) >> GSH;
  const int nGD = (n_mft + 255) >> GSH;
  const int NB = (E + CHUNK - 1) / CHUNK;

  // ---- workspace layout ----
  char* ws = (char*)d_ws;
  auto alloc = [&](size_t bytes) {
    char* p = ws;
    ws += (bytes + 255) & ~(size_t)255;
    return p;
  };
  short* h_mch = (short*)alloc((size_t)n_mch * H * 2);
  short* h_mft = (short*)alloc((size_t)n_mft * H * 2);
  short* mch1 = (short*)alloc((size_t)n_mch * H * 2);
  short* mft1 = (short*)alloc((size_t)n_mft * H * 2);
  short* mch2 = (short*)alloc((size_t)n_mch * H * 2);
  short* mft2 = (short*)alloc((size_t)n_mft * H * 2);
  int* off_mch = (int*)alloc(((size_t)n_mch + 1) * 4);
  int* off_mft = (int*)alloc(((size_t)n_mft + 1) * 4);
  int* col_mch = (int*)alloc((size_t)E * 4);
  int* col_mft = (int*)alloc((size_t)E * 4);
  int* gcntS = (int*)alloc((size_t)MAXG * 4);
  int* gcntD = (int*)alloc((size_t)MAXG * 4);
  int* GoffS = (int*)alloc(((size_t)MAXG + 1) * 4);
  int* GoffD = (int*)alloc(((size_t)MAXG + 1) * 4);
  int* baseS = (int*)alloc((size_t)NB * nGS * 4);
  int* baseD = (int*)alloc((size_t)NB * nGD * 4);
  uint2* stageS = (uint2*)alloc((size_t)E * 8);
  uint2* stageD = (uint2*)alloc((size_t)E * 8);

  float* out = (float*)d_out;

  // ---- CSR build v4 ----
  hipMemsetAsync(gcntS, 0, (size_t)MAXG * 4, stream);
  hipMemsetAsync(gcntD, 0, (size_t)MAXG * 4, stream);
  group_count_kernel<<<NB, 256, 0, stream>>>(src, dst, gcntS, gcntD, baseS, baseD,
                                             nGS, nGD, E);
  goff_scan_kernel<<<2, 512, 0, stream>>>(gcntS, GoffS, nGS, gcntD, GoffD, nGD);
  stage_scatter_kernel<<<NB, 256, 0, stream>>>(src, dst, GoffS, GoffD, baseS, baseD,
                                               stageS, stageD, nGS, nGD, E);
  finalize_group_kernel<<<nGS + nGD, 256, 0, stream>>>(
      stageS, GoffS, nGS, n_mch, off_mch, col_mch,
      stageD, GoffD, n_mft, off_mft, col_mft, E);

  // ---- input projections ----
  {
    int blk = ((n_mch * H) + 255) / 256;
    proj_kernel<<<blk, 256, 0, stream>>>(x_mch, W_mch, b_mch, h_mch, n_mch);
    blk = ((n_mft * H) + 255) / 256;
    proj_kernel<<<blk, 256, 0, stream>>>(x_mft, W_mft, b_mft, h_mft, n_mft);
  }

  // ---- convs (MFMA, both directions per launch) ----
  {
    int tiles_mft = (n_mft + 15) / 16;
    int tiles_mch = (n_mch + 15) / 16;
    int blkA = (tiles_mft + 3) / 4;
    int blkB = (tiles_mch + 3) / 4;
    sage_dual_kernel<true><<<blkA + blkB, 256, 0, stream>>>(
        h_mch, h_mft, off_mft, col_mft, c1m_Wl, c1m_bl, c1m_Wr, mft1, n_mft, blkA,
        h_mft, h_mch, off_mch, col_mch, c1r_Wl, c1r_bl, c1r_Wr, mch1, n_mch);
    sage_dual_kernel<false><<<blkA + blkB, 256, 0, stream>>>(
        mch1, mft1, off_mft, col_mft, c2m_Wl, c2m_bl, c2m_Wr, mft2, n_mft, blkA,
        mft1, mch1, off_mch, col_mch, c2r_Wl, c2r_bl, c2r_Wr, mch2, n_mch);
  }

  // ---- edge classifier (MFMA) ----
  {
    edge_mlp_mfma_kernel<<<2048, 256, 0, stream>>>(mch2, mft2, src, dst,
                                                   ec_W1, ec_b1, ec_W2, ec_b2, out, E);
  }
}

// Round 12
// 247.165 us; speedup vs baseline: 1.0659x; 1.0659x over previous
//
#include <hip/hip_runtime.h>
#include <math.h>

#define D_IN 5
#define H 64
#define GSH 8        // 256-node groups for CSR build
#define MAXG 512     // max groups per side
#define CHUNK 4096   // edges per block in count/scatter

using f32x4 = __attribute__((ext_vector_type(4))) float;
using short8 = __attribute__((ext_vector_type(8))) short;

__device__ inline short f2bf(float f) {
  unsigned u = __builtin_bit_cast(unsigned, f);
  u += 0x7fffu + ((u >> 16) & 1u);  // round-to-nearest-even
  return (short)(u >> 16);
}
__device__ inline float bf2f(short s) {
  return __builtin_bit_cast(float, ((unsigned)(unsigned short)s) << 16);
}
__device__ inline short8 cvt8(f32x4 a, f32x4 b) {
  short8 r;
  r[0] = f2bf(a[0]); r[1] = f2bf(a[1]); r[2] = f2bf(a[2]); r[3] = f2bf(a[3]);
  r[4] = f2bf(b[0]); r[5] = f2bf(b[1]); r[6] = f2bf(b[2]); r[7] = f2bf(b[3]);
  return r;
}
__device__ inline void acc16(float* m, const short8& a, const short8& b) {
#pragma unroll
  for (int i = 0; i < 8; ++i) {
    m[i] += bf2f(a[i]);
    m[8 + i] += bf2f(b[i]);
  }
}

// stage entry packing: payload (neighbor id, <2^24) | local-node-in-group << 24
#define PACK(payload, node) (((unsigned)((node) & 255) << 24) | (unsigned)(payload))

// ---------------- input projection ----------------
__global__ __launch_bounds__(256) void proj_kernel(
    const float* __restrict__ x, const float* __restrict__ W,
    const float* __restrict__ b, short* __restrict__ out, int n) {
  __shared__ float Ws[D_IN * H];
  __shared__ float bs[H];
  int t = threadIdx.x;
  for (int i = t; i < D_IN * H; i += 256) Ws[i] = W[i];
  if (t < H) bs[t] = b[t];
  __syncthreads();
  int idx = blockIdx.x * 256 + t;
  int node = idx >> 6;
  int h = idx & 63;
  if (node >= n) return;
  const float* xr = x + (size_t)node * D_IN;
  float acc = bs[h];
#pragma unroll
  for (int d = 0; d < D_IN; ++d) acc = fmaf(xr[d], Ws[d * H + h], acc);
  out[(size_t)node * H + h] = f2bf(acc);
}

// ---------------- CSR build v4: block-aggregated two-level counting sort ----------------
__global__ __launch_bounds__(256) void group_count_kernel(
    const int* __restrict__ src, const int* __restrict__ dst,
    int* __restrict__ gcntS, int* __restrict__ gcntD,
    int* __restrict__ baseS, int* __restrict__ baseD,
    int nGS, int nGD, int E) {
  __shared__ int hS[MAXG], hD[MAXG];
  int t = threadIdx.x;
  int b = blockIdx.x;
  for (int i = t; i < MAXG; i += 256) { hS[i] = 0; hD[i] = 0; }
  __syncthreads();
  int e0 = b * CHUNK;
#pragma unroll
  for (int it = 0; it < CHUNK / 1024; ++it) {
    int e = e0 + (it * 256 + t) * 4;
    if (e + 4 <= E) {
      int4 s4 = *(const int4*)(src + e);
      int4 d4 = *(const int4*)(dst + e);
      atomicAdd(&hS[s4.x >> GSH], 1);
      atomicAdd(&hS[s4.y >> GSH], 1);
      atomicAdd(&hS[s4.z >> GSH], 1);
      atomicAdd(&hS[s4.w >> GSH], 1);
      atomicAdd(&hD[d4.x >> GSH], 1);
      atomicAdd(&hD[d4.y >> GSH], 1);
      atomicAdd(&hD[d4.z >> GSH], 1);
      atomicAdd(&hD[d4.w >> GSH], 1);
    } else {
      for (int i = 0; i < 4; ++i) {
        int ee = e + i;
        if (ee < E) {
          atomicAdd(&hS[src[ee] >> GSH], 1);
          atomicAdd(&hD[dst[ee] >> GSH], 1);
        }
      }
    }
  }
  __syncthreads();
  for (int g = t; g < nGS; g += 256) {
    int h = hS[g];
    baseS[(size_t)b * nGS + g] = h ? atomicAdd(&gcntS[g], h) : 0;
  }
  for (int g = t; g < nGD; g += 256) {
    int h = hD[g];
    baseD[(size_t)b * nGD + g] = h ? atomicAdd(&gcntD[g], h) : 0;
  }
}

__global__ __launch_bounds__(512) void goff_scan_kernel(
    const int* __restrict__ gcntS, int* __restrict__ GoffS, int nGS,
    const int* __restrict__ gcntD, int* __restrict__ GoffD, int nGD) {
  const int* c = blockIdx.x ? gcntD : gcntS;
  int* G = blockIdx.x ? GoffD : GoffS;
  int n = blockIdx.x ? nGD : nGS;
  __shared__ int tmp[512];
  int t = threadIdx.x;
  int v = (t < n) ? c[t] : 0;
  tmp[t] = v;
  __syncthreads();
  for (int s = 1; s < 512; s <<= 1) {
    int add = (t >= s) ? tmp[t - s] : 0;
    __syncthreads();
    tmp[t] += add;
    __syncthreads();
  }
  if (t < n) G[t] = tmp[t] - v;
  if (t == n - 1) G[n] = tmp[t];
}

__global__ __launch_bounds__(256) void stage_scatter_kernel(
    const int* __restrict__ src, const int* __restrict__ dst,
    const int* __restrict__ GoffS, const int* __restrict__ GoffD,
    const int* __restrict__ baseS, const int* __restrict__ baseD,
    unsigned* __restrict__ stageS, unsigned* __restrict__ stageD,
    int nGS, int nGD, int E) {
  __shared__ int cS[MAXG], cD[MAXG];
  int t = threadIdx.x;
  int b = blockIdx.x;
  for (int g = t; g < nGS; g += 256) cS[g] = GoffS[g] + baseS[(size_t)b * nGS + g];
  for (int g = t; g < nGD; g += 256) cD[g] = GoffD[g] + baseD[(size_t)b * nGD + g];
  __syncthreads();
  int e0 = b * CHUNK;
#pragma unroll
  for (int it = 0; it < CHUNK / 1024; ++it) {
    int e = e0 + (it * 256 + t) * 4;
    if (e + 4 <= E) {
      int4 s4 = *(const int4*)(src + e);
      int4 d4 = *(const int4*)(dst + e);
      int pS0 = atomicAdd(&cS[s4.x >> GSH], 1);
      int pS1 = atomicAdd(&cS[s4.y >> GSH], 1);
      int pS2 = atomicAdd(&cS[s4.z >> GSH], 1);
      int pS3 = atomicAdd(&cS[s4.w >> GSH], 1);
      int pD0 = atomicAdd(&cD[d4.x >> GSH], 1);
      int pD1 = atomicAdd(&cD[d4.y >> GSH], 1);
      int pD2 = atomicAdd(&cD[d4.z >> GSH], 1);
      int pD3 = atomicAdd(&cD[d4.w >> GSH], 1);
      stageS[pS0] = PACK(d4.x, s4.x);
      stageS[pS1] = PACK(d4.y, s4.y);
      stageS[pS2] = PACK(d4.z, s4.z);
      stageS[pS3] = PACK(d4.w, s4.w);
      stageD[pD0] = PACK(s4.x, d4.x);
      stageD[pD1] = PACK(s4.y, d4.y);
      stageD[pD2] = PACK(s4.z, d4.z);
      stageD[pD3] = PACK(s4.w, d4.w);
    } else {
      for (int i = 0; i < 4; ++i) {
        int ee = e + i;
        if (ee < E) {
          int s = src[ee], d = dst[ee];
          int pS = atomicAdd(&cS[s >> GSH], 1);
          int pD = atomicAdd(&cD[d >> GSH], 1);
          stageS[pS] = PACK(d, s);
          stageD[pD] = PACK(s, d);
        }
      }
    }
  }
}

// pass D: one block per (side,group): node histogram + scan -> off[], then scatter col.
__global__ __launch_bounds__(256) void finalize_group_kernel(
    const unsigned* __restrict__ stageS, const int* __restrict__ GoffS, int nGS, int n_mch,
    int* __restrict__ off_mch, int* __restrict__ col_mch,
    const unsigned* __restrict__ stageD, const int* __restrict__ GoffD, int n_mft,
    int* __restrict__ off_mft, int* __restrict__ col_mft, int E) {
  int b = blockIdx.x;
  const unsigned* stage;
  const int* Goff;
  int n, g;
  int* off;
  int* col;
  if (b >= nGS) {
    g = b - nGS;
    stage = stageD; Goff = GoffD; n = n_mft; off = off_mft; col = col_mft;
  } else {
    g = b;
    stage = stageS; Goff = GoffS; n = n_mch; off = off_mch; col = col_mch;
  }
  int base = Goff[g];
  int cnt = Goff[g + 1] - base;
  int t = threadIdx.x;

  __shared__ int tmp[256];
  __shared__ int curs[256];
  tmp[t] = 0;
  __syncthreads();
  for (int j = t; j < cnt; j += 256) {
    unsigned p = stage[base + j];
    atomicAdd(&tmp[p >> 24], 1);
  }
  __syncthreads();
  int v = tmp[t];
  __syncthreads();
  tmp[t] = v;
  __syncthreads();
  for (int s = 1; s < 256; s <<= 1) {
    int add = (t >= s) ? tmp[t - s] : 0;
    __syncthreads();
    tmp[t] += add;
    __syncthreads();
  }
  int excl = tmp[t] - v;
  int gnode = (g << GSH) + t;
  if (gnode < n) {
    off[gnode] = base + excl;
    if (gnode == n - 1) off[n] = E;
  }
  curs[t] = base + excl;
  __syncthreads();
  for (int j = t; j < cnt; j += 256) {
    unsigned p = stage[base + j];
    int pos = atomicAdd(&curs[p >> 24], 1);
    col[pos] = (int)(p & 0xFFFFFFu);
  }
}

// ---------------- fused SAGE via MFMA: per-node registers, LDS weights, pipelined cols --
template <bool RELU>
__global__ __launch_bounds__(256) void sage_dual_kernel(
    const short* __restrict__ xsrcA, const short* __restrict__ xdstA,
    const int* __restrict__ offA, const int* __restrict__ colA,
    const float* __restrict__ WlA, const float* __restrict__ blA,
    const float* __restrict__ WrA, short* __restrict__ outA, int nA, int blkA,
    const short* __restrict__ xsrcB, const short* __restrict__ xdstB,
    const int* __restrict__ offB, const int* __restrict__ colB,
    const float* __restrict__ WlB, const float* __restrict__ blB,
    const float* __restrict__ WrB, short* __restrict__ outB, int nB) {
  bool isB = ((int)blockIdx.x >= blkA);
  int bid = isB ? (int)blockIdx.x - blkA : (int)blockIdx.x;
  const short* xsrc = isB ? xsrcB : xsrcA;
  const short* xdst = isB ? xdstB : xdstA;
  const int* off = isB ? offB : offA;
  const int* col = isB ? colB : colA;
  const float* Wl = isB ? WlB : WlA;
  const float* bl = isB ? blB : blA;
  const float* Wr = isB ? WrB : WrA;
  short* out = isB ? outB : outA;
  int n_dst = isB ? nB : nA;

  int t = threadIdx.x;
  int wave = t >> 6, lane = t & 63;
  int g = lane >> 4, c = lane & 15;

  __shared__ short8 lds_bw[4][4][64];
  for (int i = t; i < 4 * 4 * 64; i += 256) {
    int kt = i >> 8;
    int nn = (i >> 6) & 3;
    int ln = i & 63;
    int gg = ln >> 4, cc = ln & 15;
    const float* Wsrc = (kt < 2) ? Wl : Wr;
    int kbase = (kt & 1) * 32 + 8 * gg;
    short8 w;
#pragma unroll
    for (int j = 0; j < 8; ++j)
      w[j] = f2bf(Wsrc[(kbase + j) * H + 16 * nn + cc]);
    lds_bw[kt][nn][ln] = w;
  }
  __syncthreads();

  int node0 = (bid * 4 + wave) * 16;
  if (node0 >= n_dst) return;

  int mynode = node0 + c;
  int nd = (mynode < n_dst) ? mynode : 0;

  float blv[4];
#pragma unroll
  for (int n = 0; n < 4; ++n) blv[n] = bl[16 * n + c];

  // hoist root-row loads
  const short8* pr = (const short8*)(xdst + (size_t)nd * H + 8 * g);
  short8 r0 = pr[0], r1 = pr[4];

  // mean-aggregate: 4-burst rows with col indices pipelined one burst ahead
  float m[16];
#pragma unroll
  for (int i = 0; i < 16; ++i) m[i] = 0.f;
  int beg = off[nd];
  int n_nb = off[nd + 1] - beg;
  if (n_nb > 0) {
    int last = n_nb - 1;
    int i0 = col[beg];
    int i1 = col[beg + (1 < last ? 1 : last)];
    int i2 = col[beg + (2 < last ? 2 : last)];
    int i3 = col[beg + (3 < last ? 3 : last)];
    for (int jb = 0; jb < n_nb; jb += 4) {
      const short8* p0 = (const short8*)(xsrc + (size_t)i0 * H + 8 * g);
      const short8* p1 = (const short8*)(xsrc + (size_t)i1 * H + 8 * g);
      const short8* p2 = (const short8*)(xsrc + (size_t)i2 * H + 8 * g);
      const short8* p3 = (const short8*)(xsrc + (size_t)i3 * H + 8 * g);
      short8 a0 = p0[0], b0 = p0[4];
      short8 a1 = p1[0], b1 = p1[4];
      short8 a2 = p2[0], b2 = p2[4];
      short8 a3 = p3[0], b3 = p3[4];
      int jn = jb + 4;
      int n0 = i0, n1 = i1, n2 = i2, n3 = i3;
      if (jn < n_nb) {
        n0 = col[beg + jn];
        n1 = col[beg + (jn + 1 < last ? jn + 1 : last)];
        n2 = col[beg + (jn + 2 < last ? jn + 2 : last)];
        n3 = col[beg + (jn + 3 < last ? jn + 3 : last)];
      }
      int rem = n_nb - jb;
      acc16(m, a0, b0);
      if (rem > 1) acc16(m, a1, b1);
      if (rem > 2) acc16(m, a2, b2);
      if (rem > 3) acc16(m, a3, b3);
      i0 = n0; i1 = n1; i2 = n2; i3 = n3;
    }
  }
  float invd = (n_nb > 0) ? 1.f / (float)n_nb : 1.f;
  f32x4 m0, m1, m2, m3;
#pragma unroll
  for (int i = 0; i < 4; ++i) {
    m0[i] = m[i] * invd;
    m1[i] = m[4 + i] * invd;
    m2[i] = m[8 + i] * invd;
    m3[i] = m[12 + i] * invd;
  }

  short8 af[4];
  af[0] = cvt8(m0, m1);
  af[1] = cvt8(m2, m3);
  af[2] = r0;
  af[3] = r1;

  f32x4 zero4 = {0.f, 0.f, 0.f, 0.f};
  f32x4 acc[4];
#pragma unroll
  for (int n = 0; n < 4; ++n) acc[n] = zero4;
#pragma unroll
  for (int kt = 0; kt < 4; ++kt)
#pragma unroll
    for (int n = 0; n < 4; ++n)
      acc[n] = __builtin_amdgcn_mfma_f32_16x16x32_bf16(af[kt], lds_bw[kt][n][lane], acc[n], 0, 0, 0);

#pragma unroll
  for (int n = 0; n < 4; ++n)
#pragma unroll
    for (int r = 0; r < 4; ++r) {
      float o = acc[n][r] + blv[n];
      if (RELU) o = fmaxf(o, 0.f);
      int row = node0 + 4 * g + r;
      if (row < n_dst) out[(size_t)row * H + 16 * n + c] = f2bf(o);
    }
}

// ---------------- edge classifier via MFMA, LDS weights + 2-deep tile pipeline --------
__global__ __launch_bounds__(256) void edge_mlp_mfma_kernel(
    const short* __restrict__ mch2, const short* __restrict__ mft2,
    const int* __restrict__ src, const int* __restrict__ dst,
    const float* __restrict__ W1, const float* __restrict__ b1,
    const float* __restrict__ W2, const float* __restrict__ b2,
    float* __restrict__ out, int E) {
  int t = threadIdx.x;
  int wave = t >> 6, lane = t & 63;
  int g = lane >> 4, c = lane & 15;

  __shared__ short8 lds_bw[4][4][64];
  for (int i = t; i < 4 * 4 * 64; i += 256) {
    int kt = i >> 8;
    int nn = (i >> 6) & 3;
    int ln = i & 63;
    int gg = ln >> 4, cc = ln & 15;
    int kbase = 32 * kt + 8 * gg;
    short8 w;
#pragma unroll
    for (int j = 0; j < 8; ++j)
      w[j] = f2bf(W1[(kbase + j) * H + 16 * nn + cc]);
    lds_bw[kt][nn][ln] = w;
  }
  __syncthreads();

  float b1v[4], w2v[4];
#pragma unroll
  for (int n = 0; n < 4; ++n) { b1v[n] = b1[16 * n + c]; w2v[n] = W2[16 * n + c]; }
  float b2v = b2[0];
  f32x4 zero4 = {0.f, 0.f, 0.f, 0.f};

  int ntiles = (E + 15) >> 4;
  int stride = gridDim.x * 4;
  int t0 = blockIdx.x * 4 + wave;
  if (t0 >= ntiles) return;

  auto loadIdx = [&](int tile, int& s, int& d) {
    int e = tile * 16 + c;
    int ee = (e < E) ? e : E - 1;
    s = src[ee];
    d = dst[ee];
  };
  auto loadRows = [&](int s, int d, short8* af) {
    const short8* pa = (const short8*)(mch2 + (size_t)s * H + 8 * g);
    const short8* pb = (const short8*)(mft2 + (size_t)d * H + 8 * g);
    af[0] = pa[0];
    af[1] = pa[4];
    af[2] = pb[0];
    af[3] = pb[4];
  };

  int sA, dA, sB, dB;
  short8 afA[4];
  loadIdx(t0, sA, dA);
  loadRows(sA, dA, afA);
  {
    int tB = t0 + stride;
    loadIdx((tB < ntiles) ? tB : (ntiles - 1), sB, dB);
  }

  for (int tile = t0; tile < ntiles; tile += stride) {
    short8 afB[4];
    loadRows(sB, dB, afB);
    int sC, dC;
    {
      int tC = tile + 2 * stride;
      loadIdx((tC < ntiles) ? tC : (ntiles - 1), sC, dC);
    }

    f32x4 acc[4];
#pragma unroll
    for (int n = 0; n < 4; ++n) acc[n] = zero4;
#pragma unroll
    for (int kt = 0; kt < 4; ++kt)
#pragma unroll
      for (int n = 0; n < 4; ++n)
        acc[n] = __builtin_amdgcn_mfma_f32_16x16x32_bf16(afA[kt], lds_bw[kt][n][lane], acc[n], 0, 0, 0);

    float part[4];
#pragma unroll
    for (int r = 0; r < 4; ++r) {
      float sum = 0.f;
#pragma unroll
      for (int n = 0; n < 4; ++n) {
        float v = acc[n][r] + b1v[n];
        v = fmaxf(v, 0.f);
        sum = fmaf(v, w2v[n], sum);
      }
      part[r] = sum;
    }
#pragma unroll
    for (int r = 0; r < 4; ++r) {
      part[r] += __shfl_xor(part[r], 1);
      part[r] += __shfl_xor(part[r], 2);
      part[r] += __shfl_xor(part[r], 4);
      part[r] += __shfl_xor(part[r], 8);
    }
    if (c < 4) {
      int eo = tile * 16 + 4 * g + c;
      float v = (c == 0) ? part[0] : (c == 1) ? part[1] : (c == 2) ? part[2] : part[3];
      if (eo < E) out[eo] = 1.f / (1.f + expf(-(v + b2v)));
    }

#pragma unroll
    for (int i = 0; i < 4; ++i) afA[i] = afB[i];
    sB = sC;
    dB = dC;
  }
}

extern "C" void kernel_launch(void* const* d_in, const int* in_sizes, int n_in,
                              void* d_out, int out_size, void* d_ws, size_t ws_size,
                              hipStream_t stream) {
  const float* x_mch = (const float*)d_in[0];
  const float* x_mft = (const float*)d_in[1];
  const int* eidx = (const int*)d_in[2];
  const int E = in_sizes[2] / 2;
  const int* src = eidx;
  const int* dst = eidx + E;
  const float* W_mch = (const float*)d_in[3];
  const float* b_mch = (const float*)d_in[4];
  const float* W_mft = (const float*)d_in[5];
  const float* b_mft = (const float*)d_in[6];
  const float* c1m_Wl = (const float*)d_in[7];
  const float* c1m_bl = (const float*)d_in[8];
  const float* c1m_Wr = (const float*)d_in[9];
  const float* c1r_Wl = (const float*)d_in[10];
  const float* c1r_bl = (const float*)d_in[11];
  const float* c1r_Wr = (const float*)d_in[12];
  const float* c2m_Wl = (const float*)d_in[13];
  const float* c2m_bl = (const float*)d_in[14];
  const float* c2m_Wr = (const float*)d_in[15];
  const float* c2r_Wl = (const float*)d_in[16];
  const float* c2r_bl = (const float*)d_in[17];
  const float* c2r_Wr = (const float*)d_in[18];
  const float* ec_W1 = (const float*)d_in[19];
  const float* ec_b1 = (const float*)d_in[20];
  const float* ec_W2 = (const float*)d_in[21];
  const float* ec_b2 = (const float*)d_in[22];

  const int n_mch = in_sizes[0] / D_IN;
  const int n_mft = in_sizes[1] / D_IN;
  const int nGS = (n_mch + 255) >> GSH;
  const int nGD = (n_mft + 255) >> GSH;
  const int NB = (E + CHUNK - 1) / CHUNK;

  // ---- workspace layout ----
  char* ws = (char*)d_ws;
  auto alloc = [&](size_t bytes) {
    char* p = ws;
    ws += (bytes + 255) & ~(size_t)255;
    return p;
  };
  short* h_mch = (short*)alloc((size_t)n_mch * H * 2);
  short* h_mft = (short*)alloc((size_t)n_mft * H * 2);
  short* mch1 = (short*)alloc((size_t)n_mch * H * 2);
  short* mft1 = (short*)alloc((size_t)n_mft * H * 2);
  short* mch2 = (short*)alloc((size_t)n_mch * H * 2);
  short* mft2 = (short*)alloc((size_t)n_mft * H * 2);
  int* off_mch = (int*)alloc(((size_t)n_mch + 1) * 4);
  int* off_mft = (int*)alloc(((size_t)n_mft + 1) * 4);
  int* col_mch = (int*)alloc((size_t)E * 4);
  int* col_mft = (int*)alloc((size_t)E * 4);
  int* gcntS = (int*)alloc((size_t)MAXG * 4);
  int* gcntD = (int*)alloc((size_t)MAXG * 4);
  int* GoffS = (int*)alloc(((size_t)MAXG + 1) * 4);
  int* GoffD = (int*)alloc(((size_t)MAXG + 1) * 4);
  int* baseS = (int*)alloc((size_t)NB * nGS * 4);
  int* baseD = (int*)alloc((size_t)NB * nGD * 4);
  unsigned* stageS = (unsigned*)alloc((size_t)E * 4);
  unsigned* stageD = (unsigned*)alloc((size_t)E * 4);

  float* out = (float*)d_out;

  // ---- CSR build v4 ----
  hipMemsetAsync(gcntS, 0, (size_t)MAXG * 4, stream);
  hipMemsetAsync(gcntD, 0, (size_t)MAXG * 4, stream);
  group_count_kernel<<<NB, 256, 0, stream>>>(src, dst, gcntS, gcntD, baseS, baseD,
                                             nGS, nGD, E);
  goff_scan_kernel<<<2, 512, 0, stream>>>(gcntS, GoffS, nGS, gcntD, GoffD, nGD);
  stage_scatter_kernel<<<NB, 256, 0, stream>>>(src, dst, GoffS, GoffD, baseS, baseD,
                                               stageS, stageD, nGS, nGD, E);
  finalize_group_kernel<<<nGS + nGD, 256, 0, stream>>>(
      stageS, GoffS, nGS, n_mch, off_mch, col_mch,
      stageD, GoffD, n_mft, off_mft, col_mft, E);

  // ---- input projections ----
  {
    int blk = ((n_mch * H) + 255) / 256;
    proj_kernel<<<blk, 256, 0, stream>>>(x_mch, W_mch, b_mch, h_mch, n_mch);
    blk = ((n_mft * H) + 255) / 256;
    proj_kernel<<<blk, 256, 0, stream>>>(x_mft, W_mft, b_mft, h_mft, n_mft);
  }

  // ---- convs (MFMA, both directions per launch) ----
  {
    int tiles_mft = (n_mft + 15) / 16;
    int tiles_mch = (n_mch + 15) / 16;
    int blkA = (tiles_mft + 3) / 4;
    int blkB = (tiles_mch + 3) / 4;
    sage_dual_kernel<true><<<blkA + blkB, 256, 0, stream>>>(
        h_mch, h_mft, off_mft, col_mft, c1m_Wl, c1m_bl, c1m_Wr, mft1, n_mft, blkA,
        h_mft, h_mch, off_mch, col_mch, c1r_Wl, c1r_bl, c1r_Wr, mch1, n_mch);
    sage_dual_kernel<false><<<blkA + blkB, 256, 0, stream>>>(
        mch1, mft1, off_mft, col_mft, c2m_Wl, c2m_bl, c2m_Wr, mft2, n_mft, blkA,
        mft1, mch1, off_mch, col_mch, c2r_Wl, c2r_bl, c2r_Wr, mch2, n_mch);
  }

  // ---- edge classifier (MFMA) ----
  {
    edge_mlp_mfma_kernel<<<2048, 256, 0, stream>>>(mch2, mft2, src, dst,
                                                   ec_W1, ec_b1, ec_W2, ec_b2, out, E);
  }
}